// Round 12
// baseline (497.705 us; speedup 1.0000x reference)
//
#include <hip/hip_runtime.h>
#include <hip/hip_cooperative_groups.h>

namespace cg = cooperative_groups;

#define GRID_DIM 132
#define SLAB (GRID_DIM * GRID_DIM)   // 17424
#define NB 512                       // 8x8x8 bins, each 16^3 in int(t) space
#define NBLKF 1024                   // fused grid = chunks
#define CHUNKF 2048                  // points per chunk
#define KPTF (CHUNKF / 256)          // 8 points per thread, held in registers
#define TOTF (NB * NBLKF)            // 524288 seg entries
#define STRIPE 8192                  // entries per scan stripe (2^13)
#define NSTRIPEF (TOTF / STRIPE)     // 64 (exact)
#define REG 20                       // staged region edge (max tap index 19)
#define REG2 (REG * REG)
#define REG3 (REG * REG * REG)       // 8000 floats = 32 KB

__device__ __forceinline__ void bspline_w(float x, float w[4]) {
    float omx = 1.0f - x;
    w[0] = omx * omx * omx * (1.0f / 6.0f);
    w[1] = (3.0f * (x - 2.0f) * x * x + 4.0f) * (1.0f / 6.0f);
    w[2] = (-3.0f * omx * omx * (x + 1.0f) + 4.0f) * (1.0f / 6.0f);
    w[3] = x * x * x * (1.0f / 6.0f);
}

__device__ __forceinline__ void load_pt(const float* __restrict__ pts, int i,
                                        float& tx, float& ty, float& tz, bool& inb) {
    tx = pts[3 * i + 0] + 1.0f;   // ORIGIN = -(1+1e-8) == -1.0f in fp32, STEP = 1
    ty = pts[3 * i + 1] + 1.0f;
    tz = pts[3 * i + 2] + 1.0f;
    inb = (tx >= 1.0f) && (ty >= 1.0f) && (tz >= 1.0f) &&
          (tx < 130.0f) && (ty < 130.0f) && (tz < 130.0f);
    if (!inb) { tx = ty = tz = 1.0f; }
}

// 512-bin id, x-major (proven)
__device__ __forceinline__ int calc_bin(float tx, float ty, float tz) {
    int bx = min(7, ((int)tx - 1) >> 4);
    int by = min(7, ((int)ty - 1) >> 4);
    int bz = min(7, ((int)tz - 1) >> 4);
    return (bx << 6) | (by << 3) | bz;
}

// In-LDS exclusive scan of stripe totals (<=256). Barriers unconditional.
__device__ __forceinline__ void local_stripe_scan(
    const unsigned* __restrict__ stot, int nstripe,
    unsigned* soff, unsigned* sc)
{
    int t = threadIdx.x;
    if (t < 256) sc[t] = (t < nstripe) ? stot[t] : 0u;
    __syncthreads();
    for (int off = 1; off < 256; off <<= 1) {
        unsigned v = (t >= off && t < 256) ? sc[t - off] : 0u;
        __syncthreads();
        if (t < 256) sc[t] += v;
        __syncthreads();
    }
    if (t < 256) soff[t] = (t == 0) ? 0u : sc[t - 1];
    __syncthreads();
}

// ---------------- fused cooperative kernel (phases = r11-proven bodies) ----
__global__ __launch_bounds__(256, 4) void fused_kernel(
    const float* __restrict__ pts, const float* __restrict__ cp,
    float* __restrict__ out, int n,
    unsigned* __restrict__ bh, unsigned* __restrict__ seg,
    unsigned* __restrict__ stot, float4* __restrict__ sorted)
{
    __shared__ float region[REG3];                // 32 KB (phase 4)
    __shared__ unsigned lhc[NB];                  // 2 KB (hist, then cursors)
    __shared__ unsigned sc[256], soff[256];       // 2 KB

    cg::grid_group grid = cg::this_grid();
    int tid = threadIdx.x;
    int bid = blockIdx.x;
    int blk = (bid & 7) * 128 + (bid >> 3);       // bijective chunk<->XCD swizzle
    int c0 = blk * CHUNKF;

    // phase 1: per-chunk 512-bin histogram; points stay in registers
    for (int b = tid; b < NB; b += 256) lhc[b] = 0u;
    __syncthreads();
    float4 pv[KPTF];
#pragma unroll
    for (int k = 0; k < KPTF; ++k) {
        int i = c0 + tid + k * 256;
        if (i < n) {
            float tx, ty, tz; bool inb;
            load_pt(pts, i, tx, ty, tz, inb);
            unsigned tag = (unsigned)i | (inb ? 0u : 0x80000000u);
            pv[k] = make_float4(tx, ty, tz, __uint_as_float(tag));
            atomicAdd(&lhc[calc_bin(tx, ty, tz)], 1u);
        }
    }
    __syncthreads();
    for (int b = tid; b < NB; b += 256) bh[(b << 10) | blk] = lhc[b];

    grid.sync();

    // phase 2: stripe-local exclusive scans (blocks 0..63), bin-major order
    if (bid < NSTRIPEF) {
        int base_idx = bid * STRIPE + tid * 32;
        unsigned local[32];
        unsigned s = 0;
#pragma unroll
        for (int j = 0; j < 32; ++j) { unsigned v = bh[base_idx + j]; local[j] = v; s += v; }
        sc[tid] = s;
        __syncthreads();
        for (int off = 1; off < 256; off <<= 1) {
            unsigned v = (tid >= off) ? sc[tid - off] : 0u;
            __syncthreads();
            sc[tid] += v;
            __syncthreads();
        }
        unsigned run = (tid == 0) ? 0u : sc[tid - 1];
#pragma unroll
        for (int j = 0; j < 32; ++j) { seg[base_idx + j] = run; run += local[j]; }
        if (tid == 255) stot[bid] = sc[255];
    }

    grid.sync();

    // phase 3: partition from registers (no pts re-read)
    local_stripe_scan(stot, NSTRIPEF, soff, sc);
    for (int b = tid; b < NB; b += 256) {
        int idx = (b << 10) | blk;
        lhc[b] = seg[idx] + soff[idx >> 13];      // cursors
    }
    __syncthreads();
#pragma unroll
    for (int k = 0; k < KPTF; ++k) {
        int i = c0 + tid + k * 256;
        if (i < n) {
            int bin = calc_bin(pv[k].x, pv[k].y, pv[k].z);
            unsigned g = atomicAdd(&lhc[bin], 1u);
            sorted[g] = pv[k];
        }
    }

    grid.sync();

    // phase 4: eval, 2 blocks per bin (bid and bid+512 -> same XCD), region in LDS
    int sub = bid & 511, half = bid >> 9;
    int bin = (sub & 7) * 64 + (sub >> 3);        // XCD owns one x-slab
    int x0 = (bin >> 6) << 4, y0 = ((bin >> 3) & 7) << 4, z0 = (bin & 7) << 4;

    const float* src = cp + (size_t)x0 * SLAB + y0 * GRID_DIM + z0;
    for (int v = tid; v < REG3; v += 256) {
        int gx = v / REG2;
        int rr = v - gx * REG2;
        int gy = rr / REG;
        int gz = rr - gy * REG;
        region[v] = src[gx * SLAB + gy * GRID_DIM + gz];
    }
    __syncthreads();

    int i0 = bin << 10;
    unsigned s0 = seg[i0] + soff[i0 >> 13];
    unsigned e;
    if (bin == NB - 1) e = (unsigned)n;
    else { int i1 = (bin + 1) << 10; e = seg[i1] + soff[i1 >> 13]; }
    unsigned hlen = (e - s0) >> 1;
    unsigned ia = s0 + hlen * half;
    unsigned ib = half ? e : s0 + hlen;

    for (unsigned i = ia + tid; i < ib; i += 256) {
        float4 p = sorted[i];
        unsigned tag = __float_as_uint(p.w);
        int ix = (int)p.x, iy = (int)p.y, iz = (int)p.z;
        float wx[4], wy[4], wz[4];
        bspline_w(p.x - (float)ix, wx);
        bspline_w(p.y - (float)iy, wy);
        bspline_w(p.z - (float)iz, wz);
        int lx = ix - 1 - x0, ly = iy - 1 - y0, lz = iz - 1 - z0;
        const float* rb = region + (lx * REG + ly) * REG + lz;
        float acc = 0.0f;
#pragma unroll
        for (int a = 0; a < 4; ++a) {
            float accy = 0.0f;
#pragma unroll
            for (int b = 0; b < 4; ++b) {
                const float* row = rb + (a * REG + b) * REG;
                float sz = fmaf(row[0], wz[0], fmaf(row[1], wz[1],
                           fmaf(row[2], wz[2], row[3] * wz[3])));
                accy = fmaf(wy[b], sz, accy);
            }
            acc = fmaf(wx[a], accy, acc);
        }
        int orig = (int)(tag & 0x7fffffffu);
        out[orig] = (tag >> 31) ? 0.0f : acc;     // each orig written exactly once
    }
}

// ---------------- r11-proven 4-kernel fallback (same buffers, nblk=1024) ----
__global__ __launch_bounds__(256) void hist512_kernel(
    const float* __restrict__ pts, int n, unsigned* __restrict__ bh)
{
    __shared__ unsigned lh[NB];
    int tid = threadIdx.x, blk = blockIdx.x;
    int c0 = blk * CHUNKF;
    for (int b = tid; b < NB; b += 256) lh[b] = 0u;
    __syncthreads();
#pragma unroll
    for (int k = 0; k < KPTF; ++k) {
        int i = c0 + tid + k * 256;
        if (i < n) {
            float tx, ty, tz; bool inb;
            load_pt(pts, i, tx, ty, tz, inb);
            atomicAdd(&lh[calc_bin(tx, ty, tz)], 1u);
        }
    }
    __syncthreads();
    for (int b = tid; b < NB; b += 256) bh[(b << 10) | blk] = lh[b];
}

__global__ __launch_bounds__(256) void scan_l1_kernel(
    const unsigned* __restrict__ bh, unsigned* __restrict__ seg,
    unsigned* __restrict__ stot)
{
    __shared__ unsigned sc[256];
    int t = threadIdx.x;
    int base_idx = blockIdx.x * STRIPE + t * 32;
    unsigned local[32];
    unsigned s = 0;
#pragma unroll
    for (int j = 0; j < 32; ++j) { unsigned v = bh[base_idx + j]; local[j] = v; s += v; }
    sc[t] = s;
    __syncthreads();
    for (int off = 1; off < 256; off <<= 1) {
        unsigned v = (t >= off) ? sc[t - off] : 0u;
        __syncthreads();
        sc[t] += v;
        __syncthreads();
    }
    unsigned run = (t == 0) ? 0u : sc[t - 1];
#pragma unroll
    for (int j = 0; j < 32; ++j) { seg[base_idx + j] = run; run += local[j]; }
    if (t == 255) stot[blockIdx.x] = sc[255];
}

__global__ __launch_bounds__(256) void partition_kernel(
    const float* __restrict__ pts, int n,
    const unsigned* __restrict__ seg, const unsigned* __restrict__ stot,
    float4* __restrict__ sorted)
{
    __shared__ unsigned lcur[NB];
    __shared__ unsigned sc[256], soff[256];
    local_stripe_scan(stot, NSTRIPEF, soff, sc);
    int bid = blockIdx.x;
    int blk = (bid & 7) * 128 + (bid >> 3);
    int tid = threadIdx.x;
    int c0 = blk * CHUNKF;
    for (int b = tid; b < NB; b += 256) {
        int idx = (b << 10) | blk;
        lcur[b] = seg[idx] + soff[idx >> 13];
    }
    __syncthreads();
#pragma unroll
    for (int k = 0; k < KPTF; ++k) {
        int i = c0 + tid + k * 256;
        if (i < n) {
            float tx, ty, tz; bool inb;
            load_pt(pts, i, tx, ty, tz, inb);
            int bin = calc_bin(tx, ty, tz);
            unsigned g = atomicAdd(&lcur[bin], 1u);
            unsigned tag = (unsigned)i | (inb ? 0u : 0x80000000u);
            sorted[g] = make_float4(tx, ty, tz, __uint_as_float(tag));
        }
    }
}

__global__ __launch_bounds__(512) void eval_kernel(
    const float4* __restrict__ sorted, const float* __restrict__ cp,
    const unsigned* __restrict__ seg, const unsigned* __restrict__ stot,
    float* __restrict__ out, int n)
{
    __shared__ float region[REG3];
    __shared__ unsigned sc[256], soff[256];
    local_stripe_scan(stot, NSTRIPEF, soff, sc);
    int bid = blockIdx.x;
    int bin = (bid & 7) * 64 + (bid >> 3);
    int x0 = (bin >> 6) << 4, y0 = ((bin >> 3) & 7) << 4, z0 = (bin & 7) << 4;
    const float* src = cp + (size_t)x0 * SLAB + y0 * GRID_DIM + z0;
    for (int v = threadIdx.x; v < REG3; v += 512) {
        int gx = v / REG2;
        int rr = v - gx * REG2;
        int gy = rr / REG;
        int gz = rr - gy * REG;
        region[v] = src[gx * SLAB + gy * GRID_DIM + gz];
    }
    __syncthreads();
    int i0 = bin << 10;
    unsigned s = seg[i0] + soff[i0 >> 13];
    unsigned e;
    if (bin == NB - 1) e = (unsigned)n;
    else { int i1 = (bin + 1) << 10; e = seg[i1] + soff[i1 >> 13]; }
    for (unsigned i = s + threadIdx.x; i < e; i += 512) {
        float4 p = sorted[i];
        unsigned tag = __float_as_uint(p.w);
        int ix = (int)p.x, iy = (int)p.y, iz = (int)p.z;
        float wx[4], wy[4], wz[4];
        bspline_w(p.x - (float)ix, wx);
        bspline_w(p.y - (float)iy, wy);
        bspline_w(p.z - (float)iz, wz);
        int lx = ix - 1 - x0, ly = iy - 1 - y0, lz = iz - 1 - z0;
        const float* rb = region + (lx * REG + ly) * REG + lz;
        float acc = 0.0f;
#pragma unroll
        for (int a = 0; a < 4; ++a) {
            float accy = 0.0f;
#pragma unroll
            for (int b = 0; b < 4; ++b) {
                const float* row = rb + (a * REG + b) * REG;
                float sz = fmaf(row[0], wz[0], fmaf(row[1], wz[1],
                           fmaf(row[2], wz[2], row[3] * wz[3])));
                accy = fmaf(wy[b], sz, accy);
            }
            acc = fmaf(wx[a], accy, acc);
        }
        int orig = (int)(tag & 0x7fffffffu);
        out[orig] = (tag >> 31) ? 0.0f : acc;
    }
}

// Round-1 proven last-resort fallback.
__global__ __launch_bounds__(256) void eval_unsorted_kernel(
    const float* __restrict__ pts, const float* __restrict__ cp,
    float* __restrict__ out, int n)
{
    int i = blockIdx.x * blockDim.x + threadIdx.x;
    if (i >= n) return;
    float tx, ty, tz; bool inb;
    load_pt(pts, i, tx, ty, tz, inb);
    int ix = (int)tx, iy = (int)ty, iz = (int)tz;
    float wx[4], wy[4], wz[4];
    bspline_w(tx - (float)ix, wx);
    bspline_w(ty - (float)iy, wy);
    bspline_w(tz - (float)iz, wz);
    const float* bse = cp + (size_t)(ix - 1) * SLAB + (size_t)(iy - 1) * GRID_DIM + (iz - 1);
    float acc = 0.0f;
#pragma unroll
    for (int a = 0; a < 4; ++a) {
        float accy = 0.0f;
#pragma unroll
        for (int b = 0; b < 4; ++b) {
            const float* row = bse + a * SLAB + b * GRID_DIM;
            float4 v;
            __builtin_memcpy(&v, row, 16);
            float sz = fmaf(v.x, wz[0], fmaf(v.y, wz[1], fmaf(v.z, wz[2], v.w * wz[3])));
            accy = fmaf(wy[b], sz, accy);
        }
        acc = fmaf(wx[a], accy, acc);
    }
    out[i] = inb ? acc : 0.0f;
}

extern "C" void kernel_launch(void* const* d_in, const int* in_sizes, int n_in,
                              void* d_out, int out_size, void* d_ws, size_t ws_size,
                              hipStream_t stream) {
    const float* pts = (const float*)d_in[0];      // (N, 3) fp32
    const float* cp  = (const float*)d_in[1];      // (1, 132, 132, 132) fp32
    float* out       = (float*)d_out;              // (N, 1) fp32

    int n = in_sizes[0] / 3;                       // 2,000,000

    // ws layout (fully rewritten every call):
    // bh[TOTF] (2MB) | seg[TOTF] (2MB) | stot[256] | sorted float4[n]
    size_t off_seg    = (size_t)TOTF * 4;
    size_t off_stot   = off_seg + (size_t)TOTF * 4;
    size_t off_sorted = off_stot + 1024;
    size_t need       = off_sorted + (size_t)n * sizeof(float4);

    if (ws_size >= need && n <= NBLKF * CHUNKF) {
        unsigned* bh     = (unsigned*)d_ws;
        unsigned* seg    = (unsigned*)((char*)d_ws + off_seg);
        unsigned* stot   = (unsigned*)((char*)d_ws + off_stot);
        float4*   sorted = (float4*)((char*)d_ws + off_sorted);

        void* args[] = { (void*)&pts, (void*)&cp, (void*)&out, (void*)&n,
                         (void*)&bh, (void*)&seg, (void*)&stot, (void*)&sorted };
        hipError_t err = hipLaunchCooperativeKernel(
            (const void*)fused_kernel, dim3(NBLKF), dim3(256), args, 0, stream);

        if (err != hipSuccess) {
            // proven r11 pipeline on the same buffers
            hipLaunchKernelGGL(hist512_kernel, dim3(NBLKF), dim3(256), 0, stream,
                               pts, n, bh);
            hipLaunchKernelGGL(scan_l1_kernel, dim3(NSTRIPEF), dim3(256), 0, stream,
                               bh, seg, stot);
            hipLaunchKernelGGL(partition_kernel, dim3(NBLKF), dim3(256), 0, stream,
                               pts, n, seg, stot, sorted);
            hipLaunchKernelGGL(eval_kernel, dim3(NB), dim3(512), 0, stream,
                               sorted, cp, seg, stot, out, n);
        }
    } else {
        hipLaunchKernelGGL(eval_unsorted_kernel, dim3((n + 255) / 256), dim3(256), 0, stream,
                           pts, cp, out, n);
    }
}

// Round 13
// 155.115 us; speedup vs baseline: 3.2086x; 3.2086x over previous
//
#include <hip/hip_runtime.h>

#define GRID_DIM 132
#define SLAB (GRID_DIM * GRID_DIM)   // 17424
#define NB 512                       // 8x8x8 bins, each 16^3 in int(t) space
#define CHUNK 4096                   // points per partition/hist block
#define KPT (CHUNK / 256)            // 16 points per thread
#define REG 20                       // staged region edge (max tap index 19)
#define REG2 (REG * REG)
#define REG3 (REG * REG * REG)       // 8000 floats = 32 KB
#define STRIPE 8192                  // entries per scan_l1 block (2^13)

__device__ __forceinline__ void bspline_w(float x, float w[4]) {
    float omx = 1.0f - x;
    w[0] = omx * omx * omx * (1.0f / 6.0f);
    w[1] = (3.0f * (x - 2.0f) * x * x + 4.0f) * (1.0f / 6.0f);
    w[2] = (-3.0f * omx * omx * (x + 1.0f) + 4.0f) * (1.0f / 6.0f);
    w[3] = x * x * x * (1.0f / 6.0f);
}

__device__ __forceinline__ void load_pt(const float* __restrict__ pts, int i,
                                        float& tx, float& ty, float& tz, bool& inb) {
    tx = pts[3 * i + 0] + 1.0f;   // ORIGIN = -(1+1e-8) == -1.0f in fp32, STEP = 1
    ty = pts[3 * i + 1] + 1.0f;
    tz = pts[3 * i + 2] + 1.0f;
    inb = (tx >= 1.0f) && (ty >= 1.0f) && (tz >= 1.0f) &&
          (tx < 130.0f) && (ty < 130.0f) && (tz < 130.0f);
    if (!inb) { tx = ty = tz = 1.0f; }
}

// 512-bin id, x-major (proven)
__device__ __forceinline__ int calc_bin(float tx, float ty, float tz) {
    int bx = min(7, ((int)tx - 1) >> 4);
    int by = min(7, ((int)ty - 1) >> 4);
    int bz = min(7, ((int)tz - 1) >> 4);
    return (bx << 6) | (by << 3) | bz;
}

// m204 bijective XCD swizzle over chunk ids (adjacent chunks -> same XCD so
// their adjacent 128B runs assemble into full lines in that L2).
__device__ __forceinline__ int chunk_swizzle(int bid, int nblk) {
    int q = nblk >> 3, r = nblk & 7;
    int xcd = bid & 7, pos = bid >> 3;
    return (xcd < r ? xcd * (q + 1) : r * (q + 1) + (xcd - r) * q) + pos;
}

// In-LDS exclusive scan of stripe totals (<=256). Barriers unconditional.
__device__ __forceinline__ void local_stripe_scan(
    const unsigned* __restrict__ stot, int nstripe,
    unsigned* soff, unsigned* sc)
{
    int t = threadIdx.x;
    if (t < 256) sc[t] = (t < nstripe) ? stot[t] : 0u;
    __syncthreads();
    for (int off = 1; off < 256; off <<= 1) {
        unsigned v = (t >= off && t < 256) ? sc[t - off] : 0u;
        __syncthreads();
        if (t < 256) sc[t] += v;
        __syncthreads();
    }
    if (t < 256) soff[t] = (t == 0) ? 0u : sc[t - 1];
    __syncthreads();
}

// Per-chunk 512-bin histogram -> bh[bin*nblk + blk] (bin-major). No global atomics.
__global__ __launch_bounds__(256) void hist512_kernel(
    const float* __restrict__ pts, int n, int nblk, unsigned* __restrict__ bh)
{
    __shared__ unsigned lh[NB];
    int tid = threadIdx.x, blk = blockIdx.x;
    int c0 = blk * CHUNK;
    for (int b = tid; b < NB; b += 256) lh[b] = 0u;
    __syncthreads();
#pragma unroll
    for (int k = 0; k < KPT; ++k) {
        int i = c0 + tid + k * 256;
        if (i < n) {
            float tx, ty, tz; bool inb;
            load_pt(pts, i, tx, ty, tz, inb);
            atomicAdd(&lh[calc_bin(tx, ty, tz)], 1u);
        }
    }
    __syncthreads();
    for (int b = tid; b < NB; b += 256) bh[b * nblk + blk] = lh[b];
}

// Stripe-local exclusive scan (8192 entries/block) + stripe totals.
__global__ __launch_bounds__(256) void scan_l1_kernel(
    const unsigned* __restrict__ bh, unsigned* __restrict__ seg,
    unsigned* __restrict__ stot, int TOT)
{
    __shared__ unsigned sc[256];
    int t = threadIdx.x;
    int base_idx = blockIdx.x * STRIPE + t * 32;
    unsigned local[32];
    unsigned s = 0;
#pragma unroll
    for (int j = 0; j < 32; ++j) {
        int idx = base_idx + j;
        unsigned v = (idx < TOT) ? bh[idx] : 0u;
        local[j] = v; s += v;
    }
    sc[t] = s;
    __syncthreads();
    for (int off = 1; off < 256; off <<= 1) {
        unsigned v = (t >= off) ? sc[t - off] : 0u;
        __syncthreads();
        sc[t] += v;
        __syncthreads();
    }
    unsigned run = (t == 0) ? 0u : sc[t - 1];
#pragma unroll
    for (int j = 0; j < 32; ++j) {
        int idx = base_idx + j;
        if (idx < TOT) seg[idx] = run;
        run += local[j];
    }
    if (t == 255) stot[blockIdx.x] = sc[255];
}

// Bufless partition (proven r8/r11): LDS cursors seeded with deterministic
// global segment starts; one pass, direct register->global writes into
// per-(chunk,bin) runs (avg 128B with CHUNK=4096).
__global__ __launch_bounds__(256) void partition_kernel(
    const float* __restrict__ pts, int n, int nblk,
    const unsigned* __restrict__ seg, const unsigned* __restrict__ stot,
    int nstripe, float4* __restrict__ sorted)
{
    __shared__ unsigned lcur[NB];                 // 2 KB
    __shared__ unsigned sc[256], soff[256];       // 2 KB

    local_stripe_scan(stot, nstripe, soff, sc);

    int blk = chunk_swizzle(blockIdx.x, nblk);
    int tid = threadIdx.x;
    int c0 = blk * CHUNK;

    for (int b = tid; b < NB; b += 256) {
        int idx = b * nblk + blk;
        lcur[b] = seg[idx] + soff[idx >> 13];     // STRIPE = 2^13
    }
    __syncthreads();

#pragma unroll
    for (int k = 0; k < KPT; ++k) {
        int i = c0 + tid + k * 256;
        if (i < n) {
            float tx, ty, tz; bool inb;
            load_pt(pts, i, tx, ty, tz, inb);
            int bin = calc_bin(tx, ty, tz);
            unsigned g = atomicAdd(&lcur[bin], 1u);
            unsigned tag = (unsigned)i | (inb ? 0u : 0x80000000u);
            sorted[g] = make_float4(tx, ty, tz, __uint_as_float(tag));
        }
    }
}

// One 512-thread block per bin: stage the bin's 20^3 region in LDS ONCE,
// evaluate its points, write out[orig] directly (proven r11). z-dot reads
// use 3x 8B-aligned ds_read_b64 (e = lz&~1; rows start on even words since
// stride 20 is even) with parity-select -- 25% fewer LDS instructions than
// 4x ds_read_b32, identical tap values and FMA order.
__global__ __launch_bounds__(512) void eval_kernel(
    const float4* __restrict__ sorted, const float* __restrict__ cp,
    const unsigned* __restrict__ seg, const unsigned* __restrict__ stot,
    int nstripe, float* __restrict__ out, int n, int nblk)
{
    __shared__ __align__(16) float region[REG3 + 2];   // +2: corner-bin b64 over-read
    __shared__ unsigned sc[256], soff[256];

    local_stripe_scan(stot, nstripe, soff, sc);

    int bid = blockIdx.x;
    int bin = (bid & 7) * 64 + (bid >> 3);   // 512 = 8 XCDs x 64 bins
    int x0 = (bin >> 6) << 4, y0 = ((bin >> 3) & 7) << 4, z0 = (bin & 7) << 4;

    const float* src = cp + (size_t)x0 * SLAB + y0 * GRID_DIM + z0;
    for (int v = threadIdx.x; v < REG3; v += 512) {
        int gx = v / REG2;
        int rr = v - gx * REG2;
        int gy = rr / REG;
        int gz = rr - gy * REG;
        region[v] = src[gx * SLAB + gy * GRID_DIM + gz];
    }
    if (threadIdx.x < 2) region[REG3 + threadIdx.x] = 0.0f;
    __syncthreads();

    int i0 = bin * nblk;
    unsigned s = seg[i0] + soff[i0 >> 13];
    unsigned e;
    if (bin == NB - 1) e = (unsigned)n;
    else { int i1 = (bin + 1) * nblk; e = seg[i1] + soff[i1 >> 13]; }

    for (unsigned i = s + threadIdx.x; i < e; i += 512) {
        float4 p = sorted[i];
        unsigned tag = __float_as_uint(p.w);
        int ix = (int)p.x, iy = (int)p.y, iz = (int)p.z;
        float wx[4], wy[4], wz[4];
        bspline_w(p.x - (float)ix, wx);
        bspline_w(p.y - (float)iy, wy);
        bspline_w(p.z - (float)iz, wz);
        int lx = ix - 1 - x0, ly = iy - 1 - y0, lz = iz - 1 - z0;
        int ez = lz & ~1;
        int par = lz & 1;
        const float* rb = region + (lx * REG + ly) * REG + ez;
        float acc = 0.0f;
#pragma unroll
        for (int a = 0; a < 4; ++a) {
            float accy = 0.0f;
#pragma unroll
            for (int b = 0; b < 4; ++b) {
                const float2* row2 =
                    reinterpret_cast<const float2*>(rb + (a * REG + b) * REG);
                float2 s0 = row2[0], s1 = row2[1], s2 = row2[2];
                float t0 = par ? s0.y : s0.x;
                float t1 = par ? s1.x : s0.y;
                float t2 = par ? s1.y : s1.x;
                float t3 = par ? s2.x : s1.y;
                float sz = fmaf(t0, wz[0], fmaf(t1, wz[1],
                           fmaf(t2, wz[2], t3 * wz[3])));
                accy = fmaf(wy[b], sz, accy);
            }
            acc = fmaf(wx[a], accy, acc);
        }
        int orig = (int)(tag & 0x7fffffffu);
        out[orig] = (tag >> 31) ? 0.0f : acc;   // each orig written exactly once
    }
}

// Fallback (round-1 proven) if ws/config insufficient.
__global__ __launch_bounds__(256) void eval_unsorted_kernel(
    const float* __restrict__ pts, const float* __restrict__ cp,
    float* __restrict__ out, int n)
{
    int i = blockIdx.x * blockDim.x + threadIdx.x;
    if (i >= n) return;
    float tx, ty, tz; bool inb;
    load_pt(pts, i, tx, ty, tz, inb);
    int ix = (int)tx, iy = (int)ty, iz = (int)tz;
    float wx[4], wy[4], wz[4];
    bspline_w(tx - (float)ix, wx);
    bspline_w(ty - (float)iy, wy);
    bspline_w(tz - (float)iz, wz);
    const float* bse = cp + (size_t)(ix - 1) * SLAB + (size_t)(iy - 1) * GRID_DIM + (iz - 1);
    float acc = 0.0f;
#pragma unroll
    for (int a = 0; a < 4; ++a) {
        float accy = 0.0f;
#pragma unroll
        for (int b = 0; b < 4; ++b) {
            const float* row = bse + a * SLAB + b * GRID_DIM;
            float4 v;
            __builtin_memcpy(&v, row, 16);
            float sz = fmaf(v.x, wz[0], fmaf(v.y, wz[1], fmaf(v.z, wz[2], v.w * wz[3])));
            accy = fmaf(wy[b], sz, accy);
        }
        acc = fmaf(wx[a], accy, acc);
    }
    out[i] = inb ? acc : 0.0f;
}

extern "C" void kernel_launch(void* const* d_in, const int* in_sizes, int n_in,
                              void* d_out, int out_size, void* d_ws, size_t ws_size,
                              hipStream_t stream) {
    const float* pts = (const float*)d_in[0];      // (N, 3) fp32
    const float* cp  = (const float*)d_in[1];      // (1, 132, 132, 132) fp32
    float* out       = (float*)d_out;              // (N, 1) fp32

    int n = in_sizes[0] / 3;                       // 2,000,000
    int nblk = (n + CHUNK - 1) / CHUNK;            // 489
    int TOT = NB * nblk;                           // 250,368
    int nstripe = (TOT + STRIPE - 1) / STRIPE;     // 31

    // ws layout (all fully rewritten every call; no memsets needed):
    // bh[TOT] | seg[TOT] | stot[256] | sorted f4[n]
    size_t A          = (((size_t)TOT * 4) + 1023) & ~(size_t)1023;
    size_t off_seg    = A;
    size_t off_stot   = 2 * A;
    size_t off_sorted = 2 * A + 1024;
    size_t need       = off_sorted + (size_t)n * sizeof(float4);

    if (ws_size >= need && nblk <= 1024 && nstripe <= 256) {
        unsigned* bh     = (unsigned*)d_ws;
        unsigned* seg    = (unsigned*)((char*)d_ws + off_seg);
        unsigned* stot   = (unsigned*)((char*)d_ws + off_stot);
        float4*   sorted = (float4*)((char*)d_ws + off_sorted);

        hipLaunchKernelGGL(hist512_kernel, dim3(nblk), dim3(256), 0, stream,
                           pts, n, nblk, bh);
        hipLaunchKernelGGL(scan_l1_kernel, dim3(nstripe), dim3(256), 0, stream,
                           bh, seg, stot, TOT);
        hipLaunchKernelGGL(partition_kernel, dim3(nblk), dim3(256), 0, stream,
                           pts, n, nblk, seg, stot, nstripe, sorted);
        hipLaunchKernelGGL(eval_kernel, dim3(NB), dim3(512), 0, stream,
                           sorted, cp, seg, stot, nstripe, out, n, nblk);
    } else {
        hipLaunchKernelGGL(eval_unsorted_kernel, dim3((n + 255) / 256), dim3(256), 0, stream,
                           pts, cp, out, n);
    }
}